// Round 6
// baseline (1428.867 us; speedup 1.0000x reference)
//
#include <hip/hip_runtime.h>

#define K_CODES 1024
#define DIMS    256
#define NROWS   32768   // B*H*W = 32*32*32

#define BM      64      // rows per block
#define BN      128     // codes per block (chunk)
#define NCHUNK  (K_CODES / BN)   // 8
#define DK      32      // d-slice staged in LDS per step
#define PITCH   36      // verified round 2: benign bank behavior, 0-ish conflicts

// ws layout (float units)
#define WS_ESQ   0
#define WS_XSQ   (WS_ESQ + K_CODES)               // +1024
#define WS_CAND  (WS_XSQ + NROWS)                 // +32768
#define WS_NEED_FLOATS (WS_CAND + NCHUNK * NROWS * 2)
#define WS_NEED_BYTES  ((size_t)WS_NEED_FLOATS * 4)

// ---------------------------------------------------------------------------
// numpy-bitwise sum of squares of a 256-element row (verified round 2).
// ---------------------------------------------------------------------------
__device__ __forceinline__ float sq_at(const float* p, int d, int stride) {
#pragma clang fp contract(off)
    const float v = p[(size_t)d * stride];
    return v * v;
}

__device__ __forceinline__ float np_block_sq(const float* p, int stride, int o, int n) {
#pragma clang fp contract(off)
    float r[8];
    #pragma unroll
    for (int k = 0; k < 8; ++k) r[k] = sq_at(p, o + k, stride);
    const int n8 = n - (n % 8);
    for (int i = 8; i < n8; i += 8) {
        #pragma unroll
        for (int k = 0; k < 8; ++k) r[k] = r[k] + sq_at(p, o + i + k, stride);
    }
    float res = ((r[0] + r[1]) + (r[2] + r[3])) + ((r[4] + r[5]) + (r[6] + r[7]));
    for (int i = n8; i < n; ++i) res = res + sq_at(p, o + i, stride);
    return res;
}

__device__ __forceinline__ float np_sumsq_row(const float* p, int stride) {
#pragma clang fp contract(off)
    const float p120 = np_block_sq(p, stride, 1,   120);
    const float p64  = np_block_sq(p, stride, 121, 64);
    const float p71  = np_block_sq(p, stride, 185, 71);
    const float s135 = p64 + p71;
    const float s255 = p120 + s135;
    return sq_at(p, 0, stride) + s255;
}

// ---------------- x_sq ------------------------------------------------------
__global__ void vq_xsq_kernel(const float* __restrict__ x, float* __restrict__ xsq) {
    const int n = blockIdx.x * 256 + threadIdx.x;
    const float* p = x + ((size_t)(n >> 10)) * (DIMS * 1024) + (n & 1023);
    xsq[n] = np_sumsq_row(p, 1024);
}

// ---------------- e_sq ------------------------------------------------------
__global__ void vq_esq_kernel(const float* __restrict__ cb, float* __restrict__ esq) {
    const int c = blockIdx.x * 256 + threadIdx.x;
    esq[c] = np_sumsq_row(cb + (size_t)c * DIMS, 1);
}

// ---------------- main v3: round-2 block logic, code-split across blocks ----
// Outer-product register tile (4 rows x 8 codes per thread): 12 operand loads
// feed 32 FMAs -> operand-delivery pipes (LDS/VMEM) run well under the FMA
// pipe, unlike the lane=code layout (1 load per FMA, K$-BW-bound at 52%).
// Grid = 512 slices x 8 code-chunks = 4096 blocks (16/CU) fixes round-2's
// 24% occupancy. Per-(row,code) FMA chain identical (ascending d, sequential).
__global__ __launch_bounds__(256, 6)
void vq_main3_kernel(const float* __restrict__ x, const float* __restrict__ cb,
                     const float* __restrict__ esq, const float* __restrict__ xsq,
                     float2* __restrict__ cand) {
    __shared__ float xs[BM * PITCH];        // 9216 B

    const int t     = threadIdx.x;
    const int tc    = t & 15;               // code-group 0..15
    const int tr    = t >> 4;               // row-group 0..15 (4 rows each)
    const int slice = blockIdx.x >> 3;      // 0..511
    const int chunk = blockIdx.x & 7;       // 0..7 code chunk
    const int row0  = slice * BM;           // 64 | 1024 -> whole block in one image
    const int b     = row0 >> 10;
    const int hw0   = row0 & 1023;
    const float* xb = x + (size_t)b * DIMS * 1024 + hw0;

    float xsqr[4];
    #pragma unroll
    for (int i = 0; i < 4; ++i) xsqr[i] = xsq[row0 + tr * 4 + i];

    const float* ep[8];
    #pragma unroll
    for (int j = 0; j < 8; ++j)
        ep[j] = cb + (size_t)(chunk * BN + tc + 16 * j) * DIMS;

    float acc[4][8];
    #pragma unroll
    for (int i = 0; i < 4; ++i)
        #pragma unroll
        for (int j = 0; j < 8; ++j) acc[i][j] = 0.0f;

    for (int dk = 0; dk < DIMS / DK; ++dk) {
        __syncthreads();   // previous readers of xs done
        #pragma unroll
        for (int ii = 0; ii < 2; ++ii) {
            const int li = t + 256 * ii;                  // 0..511
            const int d  = (li >> 2) & 31;
            const int h4 = (li & 3) | ((li >> 7) << 2);   // 0..15
            const float4 v = *reinterpret_cast<const float4*>(
                xb + (size_t)(dk * DK + d) * 1024 + h4 * 4);
            xs[(h4 * 4 + 0) * PITCH + d] = v.x;
            xs[(h4 * 4 + 1) * PITCH + d] = v.y;
            xs[(h4 * 4 + 2) * PITCH + d] = v.z;
            xs[(h4 * 4 + 3) * PITCH + d] = v.w;
        }
        __syncthreads();

        // dot accumulation: strict ascending-d sequential FMA per (row, code).
        // j split 0..3 / 4..7 halves live e-regs (fits 6-wave VGPR budget);
        // reorders only ACROSS accumulators -> bitwise identical per acc.
        #pragma unroll
        for (int d4 = 0; d4 < DK; d4 += 4) {
            float4 xv[4];
            #pragma unroll
            for (int i = 0; i < 4; ++i)
                xv[i] = *reinterpret_cast<const float4*>(&xs[(tr * 4 + i) * PITCH + d4]);
            #pragma unroll
            for (int jh = 0; jh < 2; ++jh) {
                float4 ev[4];
                #pragma unroll
                for (int j = 0; j < 4; ++j)
                    ev[j] = *reinterpret_cast<const float4*>(ep[jh * 4 + j] + dk * DK + d4);
                #pragma unroll
                for (int i = 0; i < 4; ++i) {
                    #pragma unroll
                    for (int j = 0; j < 4; ++j) {
                        float& a = acc[i][jh * 4 + j];
                        a = fmaf(xv[i].x, ev[j].x, a);
                        a = fmaf(xv[i].y, ev[j].y, a);
                        a = fmaf(xv[i].z, ev[j].z, a);
                        a = fmaf(xv[i].w, ev[j].w, a);
                    }
                }
            }
        }
    }

    // epilogue: d2 = fl(fl(x_sq - 2*dot) + e_sq), exact np op order;
    // in-thread first-min over ascending j, then cross-tc lexmin via LDS.
    float bestv[4];
    int   bestc[4];
    #pragma unroll
    for (int i = 0; i < 4; ++i) { bestv[i] = 3.4e38f; bestc[i] = 0; }
    {
#pragma clang fp contract(off)
        #pragma unroll
        for (int j = 0; j < 8; ++j) {
            const int c = chunk * BN + tc + 16 * j;
            const float es = esq[c];
            #pragma unroll
            for (int i = 0; i < 4; ++i) {
                const float t3 = xsqr[i] - 2.0f * acc[i][j];
                const float v  = t3 + es;
                if (v < bestv[i]) { bestv[i] = v; bestc[i] = c; }
            }
        }
    }

    __syncthreads();
    float* rv = xs;                                     // 1024 floats
    int*   rc = reinterpret_cast<int*>(xs + BM * 16);   // next 1024 ints
    #pragma unroll
    for (int i = 0; i < 4; ++i) {
        const int r = tr * 4 + i;
        rv[r * 16 + tc] = bestv[i];
        rc[r * 16 + tc] = bestc[i];
    }
    __syncthreads();
    if (t < BM) {
        float bv = rv[t * 16];
        int   bc = rc[t * 16];
        #pragma unroll
        for (int k = 1; k < 16; ++k) {
            const float v = rv[t * 16 + k];
            const int   c = rc[t * 16 + k];
            if (v < bv || (v == bv && c < bc)) { bv = v; bc = c; }
        }
        cand[(size_t)chunk * NROWS + row0 + t] = make_float2(bv, __int_as_float(bc));
    }
}

// ---------------- cross-chunk lexmin reduce (chunks ascending in code) ------
__global__ void vq_reduce8_kernel(const float2* __restrict__ cand, int* __restrict__ out) {
    const int row = blockIdx.x * 256 + threadIdx.x;
    float2 p = cand[row];
    float bv = p.x; int bc = __float_as_int(p.y);
    #pragma unroll
    for (int gg = 1; gg < NCHUNK; ++gg) {
        const float2 q = cand[(size_t)gg * NROWS + row];
        const float v = q.x; const int qc = __float_as_int(q.y);
        if (v < bv || (v == bv && qc < bc)) { bv = v; bc = qc; }
    }
    out[row] = bc;
}

// ===========================================================================
// Fallback path (round-2 kernel, verified passing) — used if ws too small.
// ===========================================================================
__global__ __launch_bounds__(256, 2)
void vq_main_kernel(const float* __restrict__ x, const float* __restrict__ cb,
                    const float* __restrict__ esq, const float* __restrict__ xsq,
                    int* __restrict__ out) {
    __shared__ float xs[BM * PITCH];

    const int t   = threadIdx.x;
    const int tc  = t & 15;
    const int tr  = t >> 4;
    const int row0 = blockIdx.x * BM;
    const int b   = row0 >> 10;
    const int hw0 = row0 & 1023;
    const float* xb = x + (size_t)b * DIMS * 1024 + hw0;

    float xsqr[4];
    #pragma unroll
    for (int i = 0; i < 4; ++i) xsqr[i] = xsq[row0 + tr * 4 + i];

    float bestv[4];
    int   bestc[4];
    #pragma unroll
    for (int i = 0; i < 4; ++i) { bestv[i] = 3.4e38f; bestc[i] = 0; }

    for (int cc = 0; cc < K_CODES / BN; ++cc) {
        const float* ep[8];
        #pragma unroll
        for (int j = 0; j < 8; ++j)
            ep[j] = cb + (size_t)(cc * BN + tc + 16 * j) * DIMS;

        float acc[4][8];
        #pragma unroll
        for (int i = 0; i < 4; ++i)
            #pragma unroll
            for (int j = 0; j < 8; ++j) acc[i][j] = 0.0f;

        for (int dk = 0; dk < DIMS / DK; ++dk) {
            __syncthreads();
            #pragma unroll
            for (int ii = 0; ii < 2; ++ii) {
                const int li = t + 256 * ii;
                const int d  = (li >> 2) & 31;
                const int h4 = (li & 3) | ((li >> 7) << 2);
                const float4 v = *reinterpret_cast<const float4*>(
                    xb + (size_t)(dk * DK + d) * 1024 + h4 * 4);
                xs[(h4 * 4 + 0) * PITCH + d] = v.x;
                xs[(h4 * 4 + 1) * PITCH + d] = v.y;
                xs[(h4 * 4 + 2) * PITCH + d] = v.z;
                xs[(h4 * 4 + 3) * PITCH + d] = v.w;
            }
            __syncthreads();

            #pragma unroll
            for (int d4 = 0; d4 < DK; d4 += 4) {
                float4 xv[4];
                #pragma unroll
                for (int i = 0; i < 4; ++i)
                    xv[i] = *reinterpret_cast<const float4*>(&xs[(tr * 4 + i) * PITCH + d4]);
                float4 ev[8];
                #pragma unroll
                for (int j = 0; j < 8; ++j)
                    ev[j] = *reinterpret_cast<const float4*>(ep[j] + dk * DK + d4);
                #pragma unroll
                for (int i = 0; i < 4; ++i) {
                    #pragma unroll
                    for (int j = 0; j < 8; ++j) {
                        acc[i][j] = fmaf(xv[i].x, ev[j].x, acc[i][j]);
                        acc[i][j] = fmaf(xv[i].y, ev[j].y, acc[i][j]);
                        acc[i][j] = fmaf(xv[i].z, ev[j].z, acc[i][j]);
                        acc[i][j] = fmaf(xv[i].w, ev[j].w, acc[i][j]);
                    }
                }
            }
        }

        {
#pragma clang fp contract(off)
            #pragma unroll
            for (int j = 0; j < 8; ++j) {
                const int c = cc * BN + tc + 16 * j;
                const float es = esq[c];
                #pragma unroll
                for (int i = 0; i < 4; ++i) {
                    const float t3 = xsqr[i] - 2.0f * acc[i][j];
                    const float v  = t3 + es;
                    if (v < bestv[i]) { bestv[i] = v; bestc[i] = c; }
                }
            }
        }
    }

    __syncthreads();
    float* rv = xs;
    int*   rc = reinterpret_cast<int*>(xs + BM * 16);
    #pragma unroll
    for (int i = 0; i < 4; ++i) {
        const int r = tr * 4 + i;
        rv[r * 16 + tc] = bestv[i];
        rc[r * 16 + tc] = bestc[i];
    }
    __syncthreads();
    if (t < BM) {
        float bv = rv[t * 16];
        int   bc = rc[t * 16];
        #pragma unroll
        for (int k = 1; k < 16; ++k) {
            const float v = rv[t * 16 + k];
            const int   cidx = rc[t * 16 + k];
            if (v < bv || (v == bv && cidx < bc)) { bv = v; bc = cidx; }
        }
        out[row0 + t] = bc;
    }
}

// ===========================================================================
extern "C" void kernel_launch(void* const* d_in, const int* in_sizes, int n_in,
                              void* d_out, int out_size, void* d_ws, size_t ws_size,
                              hipStream_t stream) {
    const float* x  = (const float*)d_in[0];   // [32, 256, 32, 32]
    const float* cb = (const float*)d_in[1];   // [1024, 256]
    int* out = (int*)d_out;                    // [32768] int32
    float* ws = (float*)d_ws;

    if (ws_size >= WS_NEED_BYTES) {
        float*  esq  = ws + WS_ESQ;
        float*  xsq  = ws + WS_XSQ;
        float2* cand = (float2*)(ws + WS_CAND);

        vq_xsq_kernel<<<NROWS / 256, 256, 0, stream>>>(x, xsq);
        vq_esq_kernel<<<K_CODES / 256, 256, 0, stream>>>(cb, esq);
        vq_main3_kernel<<<(NROWS / BM) * NCHUNK, 256, 0, stream>>>(x, cb, esq, xsq, cand);
        vq_reduce8_kernel<<<NROWS / 256, 256, 0, stream>>>(cand, out);
    } else {
        float* esq = ws;
        float* xsq = ws + K_CODES;
        vq_xsq_kernel<<<NROWS / 256, 256, 0, stream>>>(x, xsq);
        vq_esq_kernel<<<K_CODES / 256, 256, 0, stream>>>(cb, esq);
        vq_main_kernel<<<NROWS / BM, 256, 0, stream>>>(x, cb, esq, xsq, out);
    }
}

// Round 7
// 1014.598 us; speedup vs baseline: 1.4083x; 1.4083x over previous
//
#include <hip/hip_runtime.h>

#define K_CODES 1024
#define DIMS    256
#define NROWS   32768   // B*H*W = 32*32*32

#define BM      64      // rows per block
#define BN      128     // codes per block (chunk)
#define NCHUNK  (K_CODES / BN)   // 8
#define DK      32      // d-slice staged in LDS per step
#define PITCH   36      // verified round 2: benign bank behavior

// ws layout (float units)
#define WS_ESQ   0
#define WS_XSQ   (WS_ESQ + K_CODES)               // +1024
#define WS_CAND  (WS_XSQ + NROWS)                 // +32768
#define WS_NEED_FLOATS (WS_CAND + NCHUNK * NROWS * 2)
#define WS_NEED_BYTES  ((size_t)WS_NEED_FLOATS * 4)

// ---------------------------------------------------------------------------
// numpy-bitwise sum of squares of a 256-element row (verified round 2).
// ---------------------------------------------------------------------------
__device__ __forceinline__ float sq_at(const float* p, int d, int stride) {
#pragma clang fp contract(off)
    const float v = p[(size_t)d * stride];
    return v * v;
}

__device__ __forceinline__ float np_block_sq(const float* p, int stride, int o, int n) {
#pragma clang fp contract(off)
    float r[8];
    #pragma unroll
    for (int k = 0; k < 8; ++k) r[k] = sq_at(p, o + k, stride);
    const int n8 = n - (n % 8);
    for (int i = 8; i < n8; i += 8) {
        #pragma unroll
        for (int k = 0; k < 8; ++k) r[k] = r[k] + sq_at(p, o + i + k, stride);
    }
    float res = ((r[0] + r[1]) + (r[2] + r[3])) + ((r[4] + r[5]) + (r[6] + r[7]));
    for (int i = n8; i < n; ++i) res = res + sq_at(p, o + i, stride);
    return res;
}

__device__ __forceinline__ float np_sumsq_row(const float* p, int stride) {
#pragma clang fp contract(off)
    const float p120 = np_block_sq(p, stride, 1,   120);
    const float p64  = np_block_sq(p, stride, 121, 64);
    const float p71  = np_block_sq(p, stride, 185, 71);
    const float s135 = p64 + p71;
    const float s255 = p120 + s135;
    return sq_at(p, 0, stride) + s255;
}

// ---------------- x_sq ------------------------------------------------------
__global__ void vq_xsq_kernel(const float* __restrict__ x, float* __restrict__ xsq) {
    const int n = blockIdx.x * 256 + threadIdx.x;
    const float* p = x + ((size_t)(n >> 10)) * (DIMS * 1024) + (n & 1023);
    xsq[n] = np_sumsq_row(p, 1024);
}

// ---------------- e_sq ------------------------------------------------------
__global__ void vq_esq_kernel(const float* __restrict__ cb, float* __restrict__ esq) {
    const int c = blockIdx.x * 256 + threadIdx.x;
    esq[c] = np_sumsq_row(cb + (size_t)c * DIMS, 1);
}

// ---------------- main v3: round-2 block logic, code-split across blocks ----
// Outer-product register tile (4 rows x 8 codes per thread).
// launch_bounds(256,4): VGPR cap 128 — round 6's (256,6) capped at 85 and
// SPILLED the acc tile to scratch (2 GB writes, 1472 us). Round-2 measured
// footprint for this body is ~88 VGPR; never cap below that.
__global__ __launch_bounds__(256, 4)
void vq_main3_kernel(const float* __restrict__ x, const float* __restrict__ cb,
                     const float* __restrict__ esq, const float* __restrict__ xsq,
                     float2* __restrict__ cand) {
    __shared__ float xs[BM * PITCH];        // 9216 B

    const int t     = threadIdx.x;
    const int tc    = t & 15;               // code-group 0..15
    const int tr    = t >> 4;               // row-group 0..15 (4 rows each)
    const int slice = blockIdx.x >> 3;      // 0..511
    const int chunk = blockIdx.x & 7;       // 0..7 code chunk
    const int row0  = slice * BM;           // 64 | 1024 -> whole block in one image
    const int b     = row0 >> 10;
    const int hw0   = row0 & 1023;
    const float* xb = x + (size_t)b * DIMS * 1024 + hw0;

    float xsqr[4];
    #pragma unroll
    for (int i = 0; i < 4; ++i) xsqr[i] = xsq[row0 + tr * 4 + i];

    const float* ep[8];
    #pragma unroll
    for (int j = 0; j < 8; ++j)
        ep[j] = cb + (size_t)(chunk * BN + tc + 16 * j) * DIMS;

    float acc[4][8];
    #pragma unroll
    for (int i = 0; i < 4; ++i)
        #pragma unroll
        for (int j = 0; j < 8; ++j) acc[i][j] = 0.0f;

    for (int dk = 0; dk < DIMS / DK; ++dk) {
        __syncthreads();   // previous readers of xs done
        #pragma unroll
        for (int ii = 0; ii < 2; ++ii) {
            const int li = t + 256 * ii;                  // 0..511
            const int d  = (li >> 2) & 31;
            const int h4 = (li & 3) | ((li >> 7) << 2);   // 0..15
            const float4 v = *reinterpret_cast<const float4*>(
                xb + (size_t)(dk * DK + d) * 1024 + h4 * 4);
            xs[(h4 * 4 + 0) * PITCH + d] = v.x;
            xs[(h4 * 4 + 1) * PITCH + d] = v.y;
            xs[(h4 * 4 + 2) * PITCH + d] = v.z;
            xs[(h4 * 4 + 3) * PITCH + d] = v.w;
        }
        __syncthreads();

        // dot accumulation: strict ascending-d sequential FMA per (row, code).
        // j split 0..3 / 4..7 halves live e-regs; reorders only ACROSS
        // accumulators -> bitwise identical per acc.
        #pragma unroll
        for (int d4 = 0; d4 < DK; d4 += 4) {
            float4 xv[4];
            #pragma unroll
            for (int i = 0; i < 4; ++i)
                xv[i] = *reinterpret_cast<const float4*>(&xs[(tr * 4 + i) * PITCH + d4]);
            #pragma unroll
            for (int jh = 0; jh < 2; ++jh) {
                float4 ev[4];
                #pragma unroll
                for (int j = 0; j < 4; ++j)
                    ev[j] = *reinterpret_cast<const float4*>(ep[jh * 4 + j] + dk * DK + d4);
                #pragma unroll
                for (int i = 0; i < 4; ++i) {
                    #pragma unroll
                    for (int j = 0; j < 4; ++j) {
                        float& a = acc[i][jh * 4 + j];
                        a = fmaf(xv[i].x, ev[j].x, a);
                        a = fmaf(xv[i].y, ev[j].y, a);
                        a = fmaf(xv[i].z, ev[j].z, a);
                        a = fmaf(xv[i].w, ev[j].w, a);
                    }
                }
            }
        }
    }

    // epilogue: d2 = fl(fl(x_sq - 2*dot) + e_sq), exact np op order;
    // in-thread first-min over ascending j, then cross-tc lexmin via LDS.
    float bestv[4];
    int   bestc[4];
    #pragma unroll
    for (int i = 0; i < 4; ++i) { bestv[i] = 3.4e38f; bestc[i] = 0; }
    {
#pragma clang fp contract(off)
        #pragma unroll
        for (int j = 0; j < 8; ++j) {
            const int c = chunk * BN + tc + 16 * j;
            const float es = esq[c];
            #pragma unroll
            for (int i = 0; i < 4; ++i) {
                const float t3 = xsqr[i] - 2.0f * acc[i][j];
                const float v  = t3 + es;
                if (v < bestv[i]) { bestv[i] = v; bestc[i] = c; }
            }
        }
    }

    __syncthreads();
    float* rv = xs;                                     // 1024 floats
    int*   rc = reinterpret_cast<int*>(xs + BM * 16);   // next 1024 ints
    #pragma unroll
    for (int i = 0; i < 4; ++i) {
        const int r = tr * 4 + i;
        rv[r * 16 + tc] = bestv[i];
        rc[r * 16 + tc] = bestc[i];
    }
    __syncthreads();
    if (t < BM) {
        float bv = rv[t * 16];
        int   bc = rc[t * 16];
        #pragma unroll
        for (int k = 1; k < 16; ++k) {
            const float v = rv[t * 16 + k];
            const int   c = rc[t * 16 + k];
            if (v < bv || (v == bv && c < bc)) { bv = v; bc = c; }
        }
        cand[(size_t)chunk * NROWS + row0 + t] = make_float2(bv, __int_as_float(bc));
    }
}

// ---------------- cross-chunk lexmin reduce (chunks ascending in code) ------
__global__ void vq_reduce8_kernel(const float2* __restrict__ cand, int* __restrict__ out) {
    const int row = blockIdx.x * 256 + threadIdx.x;
    float2 p = cand[row];
    float bv = p.x; int bc = __float_as_int(p.y);
    #pragma unroll
    for (int gg = 1; gg < NCHUNK; ++gg) {
        const float2 q = cand[(size_t)gg * NROWS + row];
        const float v = q.x; const int qc = __float_as_int(q.y);
        if (v < bv || (v == bv && qc < bc)) { bv = v; bc = qc; }
    }
    out[row] = bc;
}

// ===========================================================================
// Fallback path (round-2 kernel, verified passing) — used if ws too small.
// ===========================================================================
__global__ __launch_bounds__(256, 2)
void vq_main_kernel(const float* __restrict__ x, const float* __restrict__ cb,
                    const float* __restrict__ esq, const float* __restrict__ xsq,
                    int* __restrict__ out) {
    __shared__ float xs[BM * PITCH];

    const int t   = threadIdx.x;
    const int tc  = t & 15;
    const int tr  = t >> 4;
    const int row0 = blockIdx.x * BM;
    const int b   = row0 >> 10;
    const int hw0 = row0 & 1023;
    const float* xb = x + (size_t)b * DIMS * 1024 + hw0;

    float xsqr[4];
    #pragma unroll
    for (int i = 0; i < 4; ++i) xsqr[i] = xsq[row0 + tr * 4 + i];

    float bestv[4];
    int   bestc[4];
    #pragma unroll
    for (int i = 0; i < 4; ++i) { bestv[i] = 3.4e38f; bestc[i] = 0; }

    for (int cc = 0; cc < K_CODES / BN; ++cc) {
        const float* ep[8];
        #pragma unroll
        for (int j = 0; j < 8; ++j)
            ep[j] = cb + (size_t)(cc * BN + tc + 16 * j) * DIMS;

        float acc[4][8];
        #pragma unroll
        for (int i = 0; i < 4; ++i)
            #pragma unroll
            for (int j = 0; j < 8; ++j) acc[i][j] = 0.0f;

        for (int dk = 0; dk < DIMS / DK; ++dk) {
            __syncthreads();
            #pragma unroll
            for (int ii = 0; ii < 2; ++ii) {
                const int li = t + 256 * ii;
                const int d  = (li >> 2) & 31;
                const int h4 = (li & 3) | ((li >> 7) << 2);
                const float4 v = *reinterpret_cast<const float4*>(
                    xb + (size_t)(dk * DK + d) * 1024 + h4 * 4);
                xs[(h4 * 4 + 0) * PITCH + d] = v.x;
                xs[(h4 * 4 + 1) * PITCH + d] = v.y;
                xs[(h4 * 4 + 2) * PITCH + d] = v.z;
                xs[(h4 * 4 + 3) * PITCH + d] = v.w;
            }
            __syncthreads();

            #pragma unroll
            for (int d4 = 0; d4 < DK; d4 += 4) {
                float4 xv[4];
                #pragma unroll
                for (int i = 0; i < 4; ++i)
                    xv[i] = *reinterpret_cast<const float4*>(&xs[(tr * 4 + i) * PITCH + d4]);
                float4 ev[8];
                #pragma unroll
                for (int j = 0; j < 8; ++j)
                    ev[j] = *reinterpret_cast<const float4*>(ep[j] + dk * DK + d4);
                #pragma unroll
                for (int i = 0; i < 4; ++i) {
                    #pragma unroll
                    for (int j = 0; j < 8; ++j) {
                        acc[i][j] = fmaf(xv[i].x, ev[j].x, acc[i][j]);
                        acc[i][j] = fmaf(xv[i].y, ev[j].y, acc[i][j]);
                        acc[i][j] = fmaf(xv[i].z, ev[j].z, acc[i][j]);
                        acc[i][j] = fmaf(xv[i].w, ev[j].w, acc[i][j]);
                    }
                }
            }
        }

        {
#pragma clang fp contract(off)
            #pragma unroll
            for (int j = 0; j < 8; ++j) {
                const int c = cc * BN + tc + 16 * j;
                const float es = esq[c];
                #pragma unroll
                for (int i = 0; i < 4; ++i) {
                    const float t3 = xsqr[i] - 2.0f * acc[i][j];
                    const float v  = t3 + es;
                    if (v < bestv[i]) { bestv[i] = v; bestc[i] = c; }
                }
            }
        }
    }

    __syncthreads();
    float* rv = xs;
    int*   rc = reinterpret_cast<int*>(xs + BM * 16);
    #pragma unroll
    for (int i = 0; i < 4; ++i) {
        const int r = tr * 4 + i;
        rv[r * 16 + tc] = bestv[i];
        rc[r * 16 + tc] = bestc[i];
    }
    __syncthreads();
    if (t < BM) {
        float bv = rv[t * 16];
        int   bc = rc[t * 16];
        #pragma unroll
        for (int k = 1; k < 16; ++k) {
            const float v = rv[t * 16 + k];
            const int   cidx = rc[t * 16 + k];
            if (v < bv || (v == bv && cidx < bc)) { bv = v; bc = cidx; }
        }
        out[row0 + t] = bc;
    }
}

// ===========================================================================
extern "C" void kernel_launch(void* const* d_in, const int* in_sizes, int n_in,
                              void* d_out, int out_size, void* d_ws, size_t ws_size,
                              hipStream_t stream) {
    const float* x  = (const float*)d_in[0];   // [32, 256, 32, 32]
    const float* cb = (const float*)d_in[1];   // [1024, 256]
    int* out = (int*)d_out;                    // [32768] int32
    float* ws = (float*)d_ws;

    if (ws_size >= WS_NEED_BYTES) {
        float*  esq  = ws + WS_ESQ;
        float*  xsq  = ws + WS_XSQ;
        float2* cand = (float2*)(ws + WS_CAND);

        vq_xsq_kernel<<<NROWS / 256, 256, 0, stream>>>(x, xsq);
        vq_esq_kernel<<<K_CODES / 256, 256, 0, stream>>>(cb, esq);
        vq_main3_kernel<<<(NROWS / BM) * NCHUNK, 256, 0, stream>>>(x, cb, esq, xsq, cand);
        vq_reduce8_kernel<<<NROWS / 256, 256, 0, stream>>>(cand, out);
    } else {
        float* esq = ws;
        float* xsq = ws + K_CODES;
        vq_xsq_kernel<<<NROWS / 256, 256, 0, stream>>>(x, xsq);
        vq_esq_kernel<<<K_CODES / 256, 256, 0, stream>>>(cb, esq);
        vq_main_kernel<<<NROWS / BM, 256, 0, stream>>>(x, cb, esq, xsq, out);
    }
}

// Round 8
// 943.995 us; speedup vs baseline: 1.5136x; 1.0748x over previous
//
#include <hip/hip_runtime.h>

#define K_CODES 1024
#define DIMS    256
#define NROWS   32768   // B*H*W = 32*32*32

#define BM      64      // rows per block
#define BN      128     // codes per block (chunk)
#define NCHUNK  (K_CODES / BN)   // 8
#define DK      32      // d-slice staged in LDS per step
#define PITCH   36      // verified round 2: benign bank behavior

// ws layout (float units)
#define WS_ESQ   0
#define WS_XSQ   (WS_ESQ + K_CODES)               // +1024
#define WS_CAND  (WS_XSQ + NROWS)                 // +32768
#define WS_NEED_FLOATS (WS_CAND + NCHUNK * NROWS * 2)
#define WS_NEED_BYTES  ((size_t)WS_NEED_FLOATS * 4)

// ---------------------------------------------------------------------------
// numpy-bitwise sum of squares of a 256-element row (verified round 2).
// ---------------------------------------------------------------------------
__device__ __forceinline__ float sq_at(const float* p, int d, int stride) {
#pragma clang fp contract(off)
    const float v = p[(size_t)d * stride];
    return v * v;
}

__device__ __forceinline__ float np_block_sq(const float* p, int stride, int o, int n) {
#pragma clang fp contract(off)
    float r[8];
    #pragma unroll
    for (int k = 0; k < 8; ++k) r[k] = sq_at(p, o + k, stride);
    const int n8 = n - (n % 8);
    for (int i = 8; i < n8; i += 8) {
        #pragma unroll
        for (int k = 0; k < 8; ++k) r[k] = r[k] + sq_at(p, o + i + k, stride);
    }
    float res = ((r[0] + r[1]) + (r[2] + r[3])) + ((r[4] + r[5]) + (r[6] + r[7]));
    for (int i = n8; i < n; ++i) res = res + sq_at(p, o + i, stride);
    return res;
}

__device__ __forceinline__ float np_sumsq_row(const float* p, int stride) {
#pragma clang fp contract(off)
    const float p120 = np_block_sq(p, stride, 1,   120);
    const float p64  = np_block_sq(p, stride, 121, 64);
    const float p71  = np_block_sq(p, stride, 185, 71);
    const float s135 = p64 + p71;
    const float s255 = p120 + s135;
    return sq_at(p, 0, stride) + s255;
}

// ---------------- x_sq ------------------------------------------------------
__global__ void vq_xsq_kernel(const float* __restrict__ x, float* __restrict__ xsq) {
    const int n = blockIdx.x * 256 + threadIdx.x;
    const float* p = x + ((size_t)(n >> 10)) * (DIMS * 1024) + (n & 1023);
    xsq[n] = np_sumsq_row(p, 1024);
}

// ---------------- e_sq ------------------------------------------------------
__global__ void vq_esq_kernel(const float* __restrict__ cb, float* __restrict__ esq) {
    const int c = blockIdx.x * 256 + threadIdx.x;
    esq[c] = np_sumsq_row(cb + (size_t)c * DIMS, 1);
}

// ---------------- main v3: round-2 block logic, code-split across blocks ----
// Outer-product register tile (4 rows x 8 codes per thread).
// launch_bounds(256,2): rounds 6/7 showed (256,6)->VGPR40 and (256,4)->VGPR64
// both SPILL this ~90-VGPR body (allocator squeezes to the 64-reg occupancy
// bucket). (256,2) is the round-2-proven no-spill codegen (VGPR=88); actual
// occupancy is set by the 88-reg bucket (4 waves/SIMD), not by this promise.
__global__ __launch_bounds__(256, 2)
void vq_main3_kernel(const float* __restrict__ x, const float* __restrict__ cb,
                     const float* __restrict__ esq, const float* __restrict__ xsq,
                     float2* __restrict__ cand) {
    __shared__ float xs[BM * PITCH];        // 9216 B

    const int t     = threadIdx.x;
    const int tc    = t & 15;               // code-group 0..15
    const int tr    = t >> 4;               // row-group 0..15 (4 rows each)
    const int slice = blockIdx.x >> 3;      // 0..511
    const int chunk = blockIdx.x & 7;       // 0..7 code chunk
    const int row0  = slice * BM;           // 64 | 1024 -> whole block in one image
    const int b     = row0 >> 10;
    const int hw0   = row0 & 1023;
    const float* xb = x + (size_t)b * DIMS * 1024 + hw0;

    float xsqr[4];
    #pragma unroll
    for (int i = 0; i < 4; ++i) xsqr[i] = xsq[row0 + tr * 4 + i];

    const float* ep[8];
    #pragma unroll
    for (int j = 0; j < 8; ++j)
        ep[j] = cb + (size_t)(chunk * BN + tc + 16 * j) * DIMS;

    float acc[4][8];
    #pragma unroll
    for (int i = 0; i < 4; ++i)
        #pragma unroll
        for (int j = 0; j < 8; ++j) acc[i][j] = 0.0f;

    for (int dk = 0; dk < DIMS / DK; ++dk) {
        __syncthreads();   // previous readers of xs done
        #pragma unroll
        for (int ii = 0; ii < 2; ++ii) {
            const int li = t + 256 * ii;                  // 0..511
            const int d  = (li >> 2) & 31;
            const int h4 = (li & 3) | ((li >> 7) << 2);   // 0..15
            const float4 v = *reinterpret_cast<const float4*>(
                xb + (size_t)(dk * DK + d) * 1024 + h4 * 4);
            xs[(h4 * 4 + 0) * PITCH + d] = v.x;
            xs[(h4 * 4 + 1) * PITCH + d] = v.y;
            xs[(h4 * 4 + 2) * PITCH + d] = v.z;
            xs[(h4 * 4 + 3) * PITCH + d] = v.w;
        }
        __syncthreads();

        // dot accumulation: strict ascending-d sequential FMA per (row, code).
        // j split 0..3 / 4..7 halves live e-regs; reorders only ACROSS
        // accumulators -> bitwise identical per acc.
        #pragma unroll
        for (int d4 = 0; d4 < DK; d4 += 4) {
            float4 xv[4];
            #pragma unroll
            for (int i = 0; i < 4; ++i)
                xv[i] = *reinterpret_cast<const float4*>(&xs[(tr * 4 + i) * PITCH + d4]);
            #pragma unroll
            for (int jh = 0; jh < 2; ++jh) {
                float4 ev[4];
                #pragma unroll
                for (int j = 0; j < 4; ++j)
                    ev[j] = *reinterpret_cast<const float4*>(ep[jh * 4 + j] + dk * DK + d4);
                #pragma unroll
                for (int i = 0; i < 4; ++i) {
                    #pragma unroll
                    for (int j = 0; j < 4; ++j) {
                        float& a = acc[i][jh * 4 + j];
                        a = fmaf(xv[i].x, ev[j].x, a);
                        a = fmaf(xv[i].y, ev[j].y, a);
                        a = fmaf(xv[i].z, ev[j].z, a);
                        a = fmaf(xv[i].w, ev[j].w, a);
                    }
                }
            }
        }
    }

    // epilogue: d2 = fl(fl(x_sq - 2*dot) + e_sq), exact np op order;
    // in-thread first-min over ascending j, then cross-tc lexmin via LDS.
    float bestv[4];
    int   bestc[4];
    #pragma unroll
    for (int i = 0; i < 4; ++i) { bestv[i] = 3.4e38f; bestc[i] = 0; }
    {
#pragma clang fp contract(off)
        #pragma unroll
        for (int j = 0; j < 8; ++j) {
            const int c = chunk * BN + tc + 16 * j;
            const float es = esq[c];
            #pragma unroll
            for (int i = 0; i < 4; ++i) {
                const float t3 = xsqr[i] - 2.0f * acc[i][j];
                const float v  = t3 + es;
                if (v < bestv[i]) { bestv[i] = v; bestc[i] = c; }
            }
        }
    }

    __syncthreads();
    float* rv = xs;                                     // 1024 floats
    int*   rc = reinterpret_cast<int*>(xs + BM * 16);   // next 1024 ints
    #pragma unroll
    for (int i = 0; i < 4; ++i) {
        const int r = tr * 4 + i;
        rv[r * 16 + tc] = bestv[i];
        rc[r * 16 + tc] = bestc[i];
    }
    __syncthreads();
    if (t < BM) {
        float bv = rv[t * 16];
        int   bc = rc[t * 16];
        #pragma unroll
        for (int k = 1; k < 16; ++k) {
            const float v = rv[t * 16 + k];
            const int   c = rc[t * 16 + k];
            if (v < bv || (v == bv && c < bc)) { bv = v; bc = c; }
        }
        cand[(size_t)chunk * NROWS + row0 + t] = make_float2(bv, __int_as_float(bc));
    }
}

// ---------------- cross-chunk lexmin reduce (chunks ascending in code) ------
__global__ void vq_reduce8_kernel(const float2* __restrict__ cand, int* __restrict__ out) {
    const int row = blockIdx.x * 256 + threadIdx.x;
    float2 p = cand[row];
    float bv = p.x; int bc = __float_as_int(p.y);
    #pragma unroll
    for (int gg = 1; gg < NCHUNK; ++gg) {
        const float2 q = cand[(size_t)gg * NROWS + row];
        const float v = q.x; const int qc = __float_as_int(q.y);
        if (v < bv || (v == bv && qc < bc)) { bv = v; bc = qc; }
    }
    out[row] = bc;
}

// ===========================================================================
// Fallback path (round-2 kernel, verified passing) — used if ws too small.
// ===========================================================================
__global__ __launch_bounds__(256, 2)
void vq_main_kernel(const float* __restrict__ x, const float* __restrict__ cb,
                    const float* __restrict__ esq, const float* __restrict__ xsq,
                    int* __restrict__ out) {
    __shared__ float xs[BM * PITCH];

    const int t   = threadIdx.x;
    const int tc  = t & 15;
    const int tr  = t >> 4;
    const int row0 = blockIdx.x * BM;
    const int b   = row0 >> 10;
    const int hw0 = row0 & 1023;
    const float* xb = x + (size_t)b * DIMS * 1024 + hw0;

    float xsqr[4];
    #pragma unroll
    for (int i = 0; i < 4; ++i) xsqr[i] = xsq[row0 + tr * 4 + i];

    float bestv[4];
    int   bestc[4];
    #pragma unroll
    for (int i = 0; i < 4; ++i) { bestv[i] = 3.4e38f; bestc[i] = 0; }

    for (int cc = 0; cc < K_CODES / BN; ++cc) {
        const float* ep[8];
        #pragma unroll
        for (int j = 0; j < 8; ++j)
            ep[j] = cb + (size_t)(cc * BN + tc + 16 * j) * DIMS;

        float acc[4][8];
        #pragma unroll
        for (int i = 0; i < 4; ++i)
            #pragma unroll
            for (int j = 0; j < 8; ++j) acc[i][j] = 0.0f;

        for (int dk = 0; dk < DIMS / DK; ++dk) {
            __syncthreads();
            #pragma unroll
            for (int ii = 0; ii < 2; ++ii) {
                const int li = t + 256 * ii;
                const int d  = (li >> 2) & 31;
                const int h4 = (li & 3) | ((li >> 7) << 2);
                const float4 v = *reinterpret_cast<const float4*>(
                    xb + (size_t)(dk * DK + d) * 1024 + h4 * 4);
                xs[(h4 * 4 + 0) * PITCH + d] = v.x;
                xs[(h4 * 4 + 1) * PITCH + d] = v.y;
                xs[(h4 * 4 + 2) * PITCH + d] = v.z;
                xs[(h4 * 4 + 3) * PITCH + d] = v.w;
            }
            __syncthreads();

            #pragma unroll
            for (int d4 = 0; d4 < DK; d4 += 4) {
                float4 xv[4];
                #pragma unroll
                for (int i = 0; i < 4; ++i)
                    xv[i] = *reinterpret_cast<const float4*>(&xs[(tr * 4 + i) * PITCH + d4]);
                float4 ev[8];
                #pragma unroll
                for (int j = 0; j < 8; ++j)
                    ev[j] = *reinterpret_cast<const float4*>(ep[j] + dk * DK + d4);
                #pragma unroll
                for (int i = 0; i < 4; ++i) {
                    #pragma unroll
                    for (int j = 0; j < 8; ++j) {
                        acc[i][j] = fmaf(xv[i].x, ev[j].x, acc[i][j]);
                        acc[i][j] = fmaf(xv[i].y, ev[j].y, acc[i][j]);
                        acc[i][j] = fmaf(xv[i].z, ev[j].z, acc[i][j]);
                        acc[i][j] = fmaf(xv[i].w, ev[j].w, acc[i][j]);
                    }
                }
            }
        }

        {
#pragma clang fp contract(off)
            #pragma unroll
            for (int j = 0; j < 8; ++j) {
                const int c = cc * BN + tc + 16 * j;
                const float es = esq[c];
                #pragma unroll
                for (int i = 0; i < 4; ++i) {
                    const float t3 = xsqr[i] - 2.0f * acc[i][j];
                    const float v  = t3 + es;
                    if (v < bestv[i]) { bestv[i] = v; bestc[i] = c; }
                }
            }
        }
    }

    __syncthreads();
    float* rv = xs;
    int*   rc = reinterpret_cast<int*>(xs + BM * 16);
    #pragma unroll
    for (int i = 0; i < 4; ++i) {
        const int r = tr * 4 + i;
        rv[r * 16 + tc] = bestv[i];
        rc[r * 16 + tc] = bestc[i];
    }
    __syncthreads();
    if (t < BM) {
        float bv = rv[t * 16];
        int   bc = rc[t * 16];
        #pragma unroll
        for (int k = 1; k < 16; ++k) {
            const float v = rv[t * 16 + k];
            const int   cidx = rc[t * 16 + k];
            if (v < bv || (v == bv && cidx < bc)) { bv = v; bc = cidx; }
        }
        out[row0 + t] = bc;
    }
}

// ===========================================================================
extern "C" void kernel_launch(void* const* d_in, const int* in_sizes, int n_in,
                              void* d_out, int out_size, void* d_ws, size_t ws_size,
                              hipStream_t stream) {
    const float* x  = (const float*)d_in[0];   // [32, 256, 32, 32]
    const float* cb = (const float*)d_in[1];   // [1024, 256]
    int* out = (int*)d_out;                    // [32768] int32
    float* ws = (float*)d_ws;

    if (ws_size >= WS_NEED_BYTES) {
        float*  esq  = ws + WS_ESQ;
        float*  xsq  = ws + WS_XSQ;
        float2* cand = (float2*)(ws + WS_CAND);

        vq_xsq_kernel<<<NROWS / 256, 256, 0, stream>>>(x, xsq);
        vq_esq_kernel<<<K_CODES / 256, 256, 0, stream>>>(cb, esq);
        vq_main3_kernel<<<(NROWS / BM) * NCHUNK, 256, 0, stream>>>(x, cb, esq, xsq, cand);
        vq_reduce8_kernel<<<NROWS / 256, 256, 0, stream>>>(cand, out);
    } else {
        float* esq = ws;
        float* xsq = ws + K_CODES;
        vq_xsq_kernel<<<NROWS / 256, 256, 0, stream>>>(x, xsq);
        vq_esq_kernel<<<K_CODES / 256, 256, 0, stream>>>(cb, esq);
        vq_main_kernel<<<NROWS / BM, 256, 0, stream>>>(x, cb, esq, xsq, out);
    }
}

// Round 9
// 282.050 us; speedup vs baseline: 5.0660x; 3.3469x over previous
//
#include <hip/hip_runtime.h>

#define K_CODES 1024
#define DIMS    256
#define NROWS   32768   // B*H*W = 32*32*32

// ---------------- main-path geometry ----------------
#define NGROUPS       8      // code groups of 128 (2 codes per lane)
#define ROWS_PER_WAVE 32     // 1024 slices x 8 groups = 8192 waves -> 8/SIMD target
#define RP            16     // rows per pass (held in acc regs)

// ws layout (float units)
#define WS_ET    0
#define WS_ESQ   (WS_ET  + DIMS * K_CODES)        // 262144
#define WS_XSQ   (WS_ESQ + K_CODES)               // +1024
#define WS_CAND  (WS_XSQ + NROWS)                 // +32768
#define WS_NEED_FLOATS (WS_CAND + NGROUPS * NROWS * 2)
#define WS_NEED_BYTES  ((size_t)WS_NEED_FLOATS * 4)

// ---------------------------------------------------------------------------
// numpy-bitwise sum of squares of a 256-element row (verified round 2).
// ---------------------------------------------------------------------------
__device__ __forceinline__ float sq_at(const float* p, int d, int stride) {
#pragma clang fp contract(off)
    const float v = p[(size_t)d * stride];
    return v * v;
}

__device__ __forceinline__ float np_block_sq(const float* p, int stride, int o, int n) {
#pragma clang fp contract(off)
    float r[8];
    #pragma unroll
    for (int k = 0; k < 8; ++k) r[k] = sq_at(p, o + k, stride);
    const int n8 = n - (n % 8);
    for (int i = 8; i < n8; i += 8) {
        #pragma unroll
        for (int k = 0; k < 8; ++k) r[k] = r[k] + sq_at(p, o + i + k, stride);
    }
    float res = ((r[0] + r[1]) + (r[2] + r[3])) + ((r[4] + r[5]) + (r[6] + r[7]));
    for (int i = n8; i < n; ++i) res = res + sq_at(p, o + i, stride);
    return res;
}

__device__ __forceinline__ float np_sumsq_row(const float* p, int stride) {
#pragma clang fp contract(off)
    const float p120 = np_block_sq(p, stride, 1,   120);
    const float p64  = np_block_sq(p, stride, 121, 64);
    const float p71  = np_block_sq(p, stride, 185, 71);
    const float s135 = p64 + p71;
    const float s255 = p120 + s135;
    return sq_at(p, 0, stride) + s255;
}

// ---------------- x_sq ------------------------------------------------------
__global__ void vq_xsq_kernel(const float* __restrict__ x, float* __restrict__ xsq) {
    const int n = blockIdx.x * 256 + threadIdx.x;
    const float* p = x + ((size_t)(n >> 10)) * (DIMS * 1024) + (n & 1023);
    xsq[n] = np_sumsq_row(p, 1024);
}

// ---------------- e_sq ------------------------------------------------------
__global__ void vq_esq_kernel(const float* __restrict__ cb, float* __restrict__ esq) {
    const int c = blockIdx.x * 256 + threadIdx.x;
    esq[c] = np_sumsq_row(cb + (size_t)c * DIMS, 1);
}

// ---------------- codebook transpose: e_t[d][c] = cb[c][d] ------------------
__global__ void vq_tr_kernel(const float* __restrict__ cb, float* __restrict__ et) {
    __shared__ float tile[32][33];
    const int tx = threadIdx.x & 31;
    const int ty = threadIdx.x >> 5;               // 0..7
    const int c0 = (blockIdx.x & 31) * 32;         // 32 code tiles
    const int d0 = (blockIdx.x >> 5) * 32;         // 8 dim tiles
    #pragma unroll
    for (int i = 0; i < 4; ++i) {
        const int cl = ty + i * 8;
        tile[cl][tx] = cb[(size_t)(c0 + cl) * DIMS + d0 + tx];
    }
    __syncthreads();
    #pragma unroll
    for (int i = 0; i < 4; ++i) {
        const int dl = ty + i * 8;
        et[(size_t)(d0 + dl) * K_CODES + c0 + tx] = tile[tx][dl];
    }
}

// ---------------- main v4: lane = 2 codes, x via wave-uniform scalar loads --
// Round-5 structure (no barriers, no LDS, coalesced e_t loads, SMEM x) with
// 2 codes per lane: each 16-dword x s_load now feeds 32 FMAs (64 cyc) not 16
// (32 cyc) -> halves the SMEM-latency exposure per FMA that capped round 5
// at VALUBusy 52%. e double-buffered one 4-dim chunk ahead (as verified).
// launch_bounds(256,2): honest allocation (rounds 6-8: higher min-wave
// promises make the allocator squeeze to a 64-reg bucket and spill).
__global__ __launch_bounds__(256, 2)
void vq_main4_kernel(const float* __restrict__ x, const float* __restrict__ et,
                     const float* __restrict__ esq, const float* __restrict__ xsq,
                     float2* __restrict__ cand) {
    const int wid  = __builtin_amdgcn_readfirstlane((int)(threadIdx.x >> 6));
    const int lane = threadIdx.x & 63;
    const int W     = blockIdx.x * 4 + wid;        // 0..8191
    const int g     = W & (NGROUPS - 1);           // code group (128 codes)
    const int slice = W >> 3;                      // 0..1023 row slice
    const int c0    = g * 128 + lane;              // lane's first code
    const int row_base = slice * ROWS_PER_WAVE;    // 32 | 1024 -> one image
    const int b    = row_base >> 10;
    const int hw0  = row_base & 1023;
    const float* xb  = x + (size_t)b * (DIMS * 1024) + hw0;  // + d*1024 + r
    const float* etc = et + c0;                    // + d*1024 ; +64 = second code
    const float esq0 = esq[c0];
    const float esq1 = esq[c0 + 64];

    for (int rp = 0; rp < ROWS_PER_WAVE / RP; ++rp) {
        const int r0 = rp * RP;

        float acc0[RP], acc1[RP];
        #pragma unroll
        for (int r = 0; r < RP; ++r) { acc0[r] = 0.0f; acc1[r] = 0.0f; }

        // e double-buffer: 4 dims/chunk x 2 codes, coalesced dword loads
        float en[8];
        #pragma unroll
        for (int d = 0; d < 4; ++d) {
            en[d]     = etc[(size_t)d * K_CODES];
            en[4 + d] = etc[(size_t)d * K_CODES + 64];
        }

        for (int dk = 0; dk < DIMS / 4; ++dk) {
            float ec[8];
            #pragma unroll
            for (int d = 0; d < 8; ++d) ec[d] = en[d];
            if (dk < DIMS / 4 - 1) {
                #pragma unroll
                for (int d = 0; d < 4; ++d) {
                    en[d]     = etc[(size_t)((dk + 1) * 4 + d) * K_CODES];
                    en[4 + d] = etc[(size_t)((dk + 1) * 4 + d) * K_CODES + 64];
                }
            }
            // per dim: 16 wave-uniform x loads (s_load_dwordx16), 32 FMAs.
            // d ascending outer keeps each acc's fma chain = np/BLAS order.
            #pragma unroll
            for (int d = 0; d < 4; ++d) {
                float xv[RP];
                #pragma unroll
                for (int r = 0; r < RP; ++r)
                    xv[r] = xb[(size_t)(dk * 4 + d) * 1024 + r0 + r];
                #pragma unroll
                for (int r = 0; r < RP; ++r)
                    acc0[r] = fmaf(xv[r], ec[d], acc0[r]);
                #pragma unroll
                for (int r = 0; r < RP; ++r)
                    acc1[r] = fmaf(xv[r], ec[4 + d], acc1[r]);
            }
        }

        // epilogue: exact np op order; in-lane combine (lower code wins ties),
        // then exact first-index 64-lane lexmin butterfly.
        {
#pragma clang fp contract(off)
            float keepv = 0.0f; int keepc = 0;
            #pragma unroll
            for (int r = 0; r < RP; ++r) {
                const float xs_r = xsq[row_base + r0 + r];      // uniform
                const float t30 = xs_r - 2.0f * acc0[r];
                const float v0  = t30 + esq0;
                const float t31 = xs_r - 2.0f * acc1[r];
                const float v1  = t31 + esq1;
                float bv = v0; int bc = c0;
                if (v1 < bv) { bv = v1; bc = c0 + 64; }          // tie -> lower c
                #pragma unroll
                for (int off = 1; off < 64; off <<= 1) {
                    const float ov = __shfl_xor(bv, off, 64);
                    const int   oc = __shfl_xor(bc, off, 64);
                    if (ov < bv || (ov == bv && oc < bc)) { bv = ov; bc = oc; }
                }
                if (lane == r) { keepv = bv; keepc = bc; }      // lane r keeps row r
            }
            if (lane < RP) {
                cand[(size_t)g * NROWS + row_base + r0 + lane] =
                    make_float2(keepv, __int_as_float(keepc));
            }
        }
    }
}

// ---------------- cross-group lexmin reduce (groups ascending in code) ------
__global__ void vq_reduce_kernel(const float2* __restrict__ cand, int* __restrict__ out) {
    const int row = blockIdx.x * 256 + threadIdx.x;
    float2 p = cand[row];
    float bv = p.x; int bc = __float_as_int(p.y);
    #pragma unroll
    for (int gg = 1; gg < NGROUPS; ++gg) {
        const float2 q = cand[(size_t)gg * NROWS + row];
        const float v = q.x; const int qc = __float_as_int(q.y);
        if (v < bv || (v == bv && qc < bc)) { bv = v; bc = qc; }
    }
    out[row] = bc;
}

// ===========================================================================
// Fallback path (round-2 kernel, verified passing) — used if ws too small.
// ===========================================================================
#define BM      64
#define BN      128
#define DK      32
#define PITCH   36

__global__ __launch_bounds__(256, 2)
void vq_main_kernel(const float* __restrict__ x, const float* __restrict__ cb,
                    const float* __restrict__ esq, const float* __restrict__ xsq,
                    int* __restrict__ out) {
    __shared__ float xs[BM * PITCH];

    const int t   = threadIdx.x;
    const int tc  = t & 15;
    const int tr  = t >> 4;
    const int row0 = blockIdx.x * BM;
    const int b   = row0 >> 10;
    const int hw0 = row0 & 1023;
    const float* xb = x + (size_t)b * DIMS * 1024 + hw0;

    float xsqr[4];
    #pragma unroll
    for (int i = 0; i < 4; ++i) xsqr[i] = xsq[row0 + tr * 4 + i];

    float bestv[4];
    int   bestc[4];
    #pragma unroll
    for (int i = 0; i < 4; ++i) { bestv[i] = 3.4e38f; bestc[i] = 0; }

    for (int cc = 0; cc < K_CODES / BN; ++cc) {
        const float* ep[8];
        #pragma unroll
        for (int j = 0; j < 8; ++j)
            ep[j] = cb + (size_t)(cc * BN + tc + 16 * j) * DIMS;

        float acc[4][8];
        #pragma unroll
        for (int i = 0; i < 4; ++i)
            #pragma unroll
            for (int j = 0; j < 8; ++j) acc[i][j] = 0.0f;

        for (int dk = 0; dk < DIMS / DK; ++dk) {
            __syncthreads();
            #pragma unroll
            for (int ii = 0; ii < 2; ++ii) {
                const int li = t + 256 * ii;
                const int d  = (li >> 2) & 31;
                const int h4 = (li & 3) | ((li >> 7) << 2);
                const float4 v = *reinterpret_cast<const float4*>(
                    xb + (size_t)(dk * DK + d) * 1024 + h4 * 4);
                xs[(h4 * 4 + 0) * PITCH + d] = v.x;
                xs[(h4 * 4 + 1) * PITCH + d] = v.y;
                xs[(h4 * 4 + 2) * PITCH + d] = v.z;
                xs[(h4 * 4 + 3) * PITCH + d] = v.w;
            }
            __syncthreads();

            #pragma unroll
            for (int d4 = 0; d4 < DK; d4 += 4) {
                float4 xv[4];
                #pragma unroll
                for (int i = 0; i < 4; ++i)
                    xv[i] = *reinterpret_cast<const float4*>(&xs[(tr * 4 + i) * PITCH + d4]);
                float4 ev[8];
                #pragma unroll
                for (int j = 0; j < 8; ++j)
                    ev[j] = *reinterpret_cast<const float4*>(ep[j] + dk * DK + d4);
                #pragma unroll
                for (int i = 0; i < 4; ++i) {
                    #pragma unroll
                    for (int j = 0; j < 8; ++j) {
                        acc[i][j] = fmaf(xv[i].x, ev[j].x, acc[i][j]);
                        acc[i][j] = fmaf(xv[i].y, ev[j].y, acc[i][j]);
                        acc[i][j] = fmaf(xv[i].z, ev[j].z, acc[i][j]);
                        acc[i][j] = fmaf(xv[i].w, ev[j].w, acc[i][j]);
                    }
                }
            }
        }

        {
#pragma clang fp contract(off)
            #pragma unroll
            for (int j = 0; j < 8; ++j) {
                const int c = cc * BN + tc + 16 * j;
                const float es = esq[c];
                #pragma unroll
                for (int i = 0; i < 4; ++i) {
                    const float t3 = xsqr[i] - 2.0f * acc[i][j];
                    const float v  = t3 + es;
                    if (v < bestv[i]) { bestv[i] = v; bestc[i] = c; }
                }
            }
        }
    }

    __syncthreads();
    float* rv = xs;
    int*   rc = reinterpret_cast<int*>(xs + BM * 16);
    #pragma unroll
    for (int i = 0; i < 4; ++i) {
        const int r = tr * 4 + i;
        rv[r * 16 + tc] = bestv[i];
        rc[r * 16 + tc] = bestc[i];
    }
    __syncthreads();
    if (t < BM) {
        float bv = rv[t * 16];
        int   bc = rc[t * 16];
        #pragma unroll
        for (int k = 1; k < 16; ++k) {
            const float v = rv[t * 16 + k];
            const int   cidx = rc[t * 16 + k];
            if (v < bv || (v == bv && cidx < bc)) { bv = v; bc = cidx; }
        }
        out[row0 + t] = bc;
    }
}

// ===========================================================================
extern "C" void kernel_launch(void* const* d_in, const int* in_sizes, int n_in,
                              void* d_out, int out_size, void* d_ws, size_t ws_size,
                              hipStream_t stream) {
    const float* x  = (const float*)d_in[0];   // [32, 256, 32, 32]
    const float* cb = (const float*)d_in[1];   // [1024, 256]
    int* out = (int*)d_out;                    // [32768] int32
    float* ws = (float*)d_ws;

    if (ws_size >= WS_NEED_BYTES) {
        float*  et   = ws + WS_ET;
        float*  esq  = ws + WS_ESQ;
        float*  xsq  = ws + WS_XSQ;
        float2* cand = (float2*)(ws + WS_CAND);

        vq_xsq_kernel<<<NROWS / 256, 256, 0, stream>>>(x, xsq);
        vq_esq_kernel<<<K_CODES / 256, 256, 0, stream>>>(cb, esq);
        vq_tr_kernel<<<256, 256, 0, stream>>>(cb, et);
        vq_main4_kernel<<<(NROWS / ROWS_PER_WAVE) * NGROUPS / 4, 256, 0, stream>>>(
            x, et, esq, xsq, cand);
        vq_reduce_kernel<<<NROWS / 256, 256, 0, stream>>>(cand, out);
    } else {
        float* esq = ws;
        float* xsq = ws + K_CODES;
        vq_xsq_kernel<<<NROWS / 256, 256, 0, stream>>>(x, xsq);
        vq_esq_kernel<<<K_CODES / 256, 256, 0, stream>>>(cb, esq);
        vq_main_kernel<<<NROWS / BM, 256, 0, stream>>>(x, cb, esq, xsq, out);
    }
}

// Round 10
// 240.326 us; speedup vs baseline: 5.9455x; 1.1736x over previous
//
#include <hip/hip_runtime.h>

#define K_CODES 1024
#define DIMS    256
#define NROWS   32768   // B*H*W = 32*32*32

// ---------------- main-path geometry ----------------
#define NGROUPS       4      // code groups of 256 (4 codes per lane)
#define ROWS_PER_WAVE 16     // 2048 slices x 4 groups = 8192 waves
#define RP            16     // rows per (single) pass

// ws layout (float units)
#define WS_ET    0
#define WS_ESQ   (WS_ET  + DIMS * K_CODES)        // 262144 (et4: 64 x 1024 float4)
#define WS_XSQ   (WS_ESQ + K_CODES)               // +1024
#define WS_CAND  (WS_XSQ + NROWS)                 // +32768
#define WS_NEED_FLOATS (WS_CAND + NGROUPS * NROWS * 2)
#define WS_NEED_BYTES  ((size_t)WS_NEED_FLOATS * 4)

// ---------------------------------------------------------------------------
// numpy-bitwise sum of squares of a 256-element row (verified round 2).
// ---------------------------------------------------------------------------
__device__ __forceinline__ float sq_at(const float* p, int d, int stride) {
#pragma clang fp contract(off)
    const float v = p[(size_t)d * stride];
    return v * v;
}

__device__ __forceinline__ float np_block_sq(const float* p, int stride, int o, int n) {
#pragma clang fp contract(off)
    float r[8];
    #pragma unroll
    for (int k = 0; k < 8; ++k) r[k] = sq_at(p, o + k, stride);
    const int n8 = n - (n % 8);
    for (int i = 8; i < n8; i += 8) {
        #pragma unroll
        for (int k = 0; k < 8; ++k) r[k] = r[k] + sq_at(p, o + i + k, stride);
    }
    float res = ((r[0] + r[1]) + (r[2] + r[3])) + ((r[4] + r[5]) + (r[6] + r[7]));
    for (int i = n8; i < n; ++i) res = res + sq_at(p, o + i, stride);
    return res;
}

__device__ __forceinline__ float np_sumsq_row(const float* p, int stride) {
#pragma clang fp contract(off)
    const float p120 = np_block_sq(p, stride, 1,   120);
    const float p64  = np_block_sq(p, stride, 121, 64);
    const float p71  = np_block_sq(p, stride, 185, 71);
    const float s135 = p64 + p71;
    const float s255 = p120 + s135;
    return sq_at(p, 0, stride) + s255;
}

// ---------------- x_sq ------------------------------------------------------
__global__ void vq_xsq_kernel(const float* __restrict__ x, float* __restrict__ xsq) {
    const int n = blockIdx.x * 256 + threadIdx.x;
    const float* p = x + ((size_t)(n >> 10)) * (DIMS * 1024) + (n & 1023);
    xsq[n] = np_sumsq_row(p, 1024);
}

// ---------------- e_sq ------------------------------------------------------
__global__ void vq_esq_kernel(const float* __restrict__ cb, float* __restrict__ esq) {
    const int c = blockIdx.x * 256 + threadIdx.x;
    esq[c] = np_sumsq_row(cb + (size_t)c * DIMS, 1);
}

// ---------------- codebook panel transpose: et4[dk][c] = dims 4dk..4dk+3 ----
// wave = all 64 dk for one code c -> 1KB contiguous coalesced read per wave;
// scattered 16B writes are L2-absorbed (1 MB total, one-shot kernel).
__global__ void vq_tr4_kernel(const float* __restrict__ cb, float4* __restrict__ et4) {
    const int idx = blockIdx.x * 256 + threadIdx.x;   // 65536 = 64 dk x 1024 c
    const int dk  = idx & 63;
    const int c   = idx >> 6;
    const float4 v = *reinterpret_cast<const float4*>(cb + (size_t)c * DIMS + dk * 4);
    et4[(size_t)dk * K_CODES + c] = v;
}

// ---------------- main v5: 4 codes/lane, panel e-loads, ping-pong dbuf ------
// Per dk-step: 256 FMAs vs {4 dwordx4 e-loads at scalar-base + lane-invariant
// voffset + imm offset (near-zero VALU addressing), 4 s_load_dwordx16 x-loads
// (SMEM pipe, free)}. Explicit eA/eB ping-pong (dk unrolled by 2) kills the
// double-buffer v_movs of round 9. FMA chain per (row,code): one accumulator,
// strictly ascending d -> bitwise identical to np/BLAS reference order.
// launch_bounds(256,2): honest allocation (rounds 6-8: tighter promises make
// the allocator squeeze into a smaller bucket and spill the acc tile).
__global__ __launch_bounds__(256, 2)
void vq_main5_kernel(const float* __restrict__ x, const float4* __restrict__ et4,
                     const float* __restrict__ esq, const float* __restrict__ xsq,
                     float2* __restrict__ cand) {
    const int wid  = __builtin_amdgcn_readfirstlane((int)(threadIdx.x >> 6));
    const int lane = threadIdx.x & 63;
    const int W     = blockIdx.x * 4 + wid;        // 0..8191
    const int g     = W & (NGROUPS - 1);           // code group of 256
    const int slice = W >> 2;                      // 0..2047 row slice
    const int c0    = g * 256 + lane;              // lane codes: c0+{0,64,128,192}
    const int row_base = slice * ROWS_PER_WAVE;    // 16 | 1024 -> one image
    const int b    = row_base >> 10;
    const int hw0  = row_base & 1023;
    const float* xb = x + (size_t)b * (DIMS * 1024) + hw0;   // + d*1024 + r
    const float esq0 = esq[c0];
    const float esq1 = esq[c0 + 64];
    const float esq2 = esq[c0 + 128];
    const float esq3 = esq[c0 + 192];

    float acc0[RP], acc1[RP], acc2[RP], acc3[RP];
    #pragma unroll
    for (int r = 0; r < RP; ++r) { acc0[r] = 0.0f; acc1[r] = 0.0f; acc2[r] = 0.0f; acc3[r] = 0.0f; }

    // e ping-pong buffers: 4 codes x 4 dims each (constant-indexed floats)
    float eA[16], eB[16];

#define LOAD_E(BUF, DK)                                                         \
    do {                                                                        \
        const float4* p_ = et4 + (size_t)(DK) * K_CODES;                        \
        *reinterpret_cast<float4*>(&BUF[0])  = p_[c0];                          \
        *reinterpret_cast<float4*>(&BUF[4])  = p_[c0 + 64];                     \
        *reinterpret_cast<float4*>(&BUF[8])  = p_[c0 + 128];                    \
        *reinterpret_cast<float4*>(&BUF[12]) = p_[c0 + 192];                    \
    } while (0)

    // per dim: 16 wave-uniform x loads (s_load_dwordx16) feed 64 FMAs.
#define COMPUTE(DK, E)                                                          \
    do {                                                                        \
        _Pragma("unroll")                                                       \
        for (int dd = 0; dd < 4; ++dd) {                                        \
            float xv[RP];                                                       \
            _Pragma("unroll")                                                   \
            for (int r = 0; r < RP; ++r)                                        \
                xv[r] = xb[(size_t)((DK) * 4 + dd) * 1024 + r];                 \
            _Pragma("unroll")                                                   \
            for (int r = 0; r < RP; ++r) acc0[r] = fmaf(xv[r], E[dd],      acc0[r]); \
            _Pragma("unroll")                                                   \
            for (int r = 0; r < RP; ++r) acc1[r] = fmaf(xv[r], E[4 + dd],  acc1[r]); \
            _Pragma("unroll")                                                   \
            for (int r = 0; r < RP; ++r) acc2[r] = fmaf(xv[r], E[8 + dd],  acc2[r]); \
            _Pragma("unroll")                                                   \
            for (int r = 0; r < RP; ++r) acc3[r] = fmaf(xv[r], E[12 + dd], acc3[r]); \
        }                                                                       \
    } while (0)

    LOAD_E(eA, 0);
    for (int dk = 0; dk < DIMS / 4; dk += 2) {
        LOAD_E(eB, dk + 1);
        COMPUTE(dk, eA);
        if (dk + 2 < DIMS / 4) LOAD_E(eA, dk + 2);
        COMPUTE(dk + 1, eB);
    }
#undef LOAD_E
#undef COMPUTE

    // epilogue: d2 = fl(fl(x_sq - 2*dot) + e_sq), exact np op order;
    // in-lane combine ascending c (strict < -> lower code wins ties),
    // then exact first-index 64-lane lexmin butterfly.
    {
#pragma clang fp contract(off)
        float keepv = 0.0f; int keepc = 0;
        #pragma unroll
        for (int r = 0; r < RP; ++r) {
            const float xs_r = xsq[row_base + r];            // uniform
            const float v0 = (xs_r - 2.0f * acc0[r]) + esq0;
            const float v1 = (xs_r - 2.0f * acc1[r]) + esq1;
            const float v2 = (xs_r - 2.0f * acc2[r]) + esq2;
            const float v3 = (xs_r - 2.0f * acc3[r]) + esq3;
            float bv = v0; int bc = c0;
            if (v1 < bv) { bv = v1; bc = c0 + 64; }
            if (v2 < bv) { bv = v2; bc = c0 + 128; }
            if (v3 < bv) { bv = v3; bc = c0 + 192; }
            #pragma unroll
            for (int off = 1; off < 64; off <<= 1) {
                const float ov = __shfl_xor(bv, off, 64);
                const int   oc = __shfl_xor(bc, off, 64);
                if (ov < bv || (ov == bv && oc < bc)) { bv = ov; bc = oc; }
            }
            if (lane == r) { keepv = bv; keepc = bc; }       // lane r keeps row r
        }
        if (lane < RP) {
            cand[(size_t)g * NROWS + row_base + lane] =
                make_float2(keepv, __int_as_float(keepc));
        }
    }
}

// ---------------- cross-group lexmin reduce (groups ascending in code) ------
__global__ void vq_reduce_kernel(const float2* __restrict__ cand, int* __restrict__ out) {
    const int row = blockIdx.x * 256 + threadIdx.x;
    float2 p = cand[row];
    float bv = p.x; int bc = __float_as_int(p.y);
    #pragma unroll
    for (int gg = 1; gg < NGROUPS; ++gg) {
        const float2 q = cand[(size_t)gg * NROWS + row];
        const float v = q.x; const int qc = __float_as_int(q.y);
        if (v < bv || (v == bv && qc < bc)) { bv = v; bc = qc; }
    }
    out[row] = bc;
}

// ===========================================================================
// Fallback path (round-2 kernel, verified passing) — used if ws too small.
// ===========================================================================
#define BM      64
#define BN      128
#define DK      32
#define PITCH   36

__global__ __launch_bounds__(256, 2)
void vq_main_kernel(const float* __restrict__ x, const float* __restrict__ cb,
                    const float* __restrict__ esq, const float* __restrict__ xsq,
                    int* __restrict__ out) {
    __shared__ float xs[BM * PITCH];

    const int t   = threadIdx.x;
    const int tc  = t & 15;
    const int tr  = t >> 4;
    const int row0 = blockIdx.x * BM;
    const int b   = row0 >> 10;
    const int hw0 = row0 & 1023;
    const float* xb = x + (size_t)b * DIMS * 1024 + hw0;

    float xsqr[4];
    #pragma unroll
    for (int i = 0; i < 4; ++i) xsqr[i] = xsq[row0 + tr * 4 + i];

    float bestv[4];
    int   bestc[4];
    #pragma unroll
    for (int i = 0; i < 4; ++i) { bestv[i] = 3.4e38f; bestc[i] = 0; }

    for (int cc = 0; cc < K_CODES / BN; ++cc) {
        const float* ep[8];
        #pragma unroll
        for (int j = 0; j < 8; ++j)
            ep[j] = cb + (size_t)(cc * BN + tc + 16 * j) * DIMS;

        float acc[4][8];
        #pragma unroll
        for (int i = 0; i < 4; ++i)
            #pragma unroll
            for (int j = 0; j < 8; ++j) acc[i][j] = 0.0f;

        for (int dk = 0; dk < DIMS / DK; ++dk) {
            __syncthreads();
            #pragma unroll
            for (int ii = 0; ii < 2; ++ii) {
                const int li = t + 256 * ii;
                const int d  = (li >> 2) & 31;
                const int h4 = (li & 3) | ((li >> 7) << 2);
                const float4 v = *reinterpret_cast<const float4*>(
                    xb + (size_t)(dk * DK + d) * 1024 + h4 * 4);
                xs[(h4 * 4 + 0) * PITCH + d] = v.x;
                xs[(h4 * 4 + 1) * PITCH + d] = v.y;
                xs[(h4 * 4 + 2) * PITCH + d] = v.z;
                xs[(h4 * 4 + 3) * PITCH + d] = v.w;
            }
            __syncthreads();

            #pragma unroll
            for (int d4 = 0; d4 < DK; d4 += 4) {
                float4 xv[4];
                #pragma unroll
                for (int i = 0; i < 4; ++i)
                    xv[i] = *reinterpret_cast<const float4*>(&xs[(tr * 4 + i) * PITCH + d4]);
                float4 ev[8];
                #pragma unroll
                for (int j = 0; j < 8; ++j)
                    ev[j] = *reinterpret_cast<const float4*>(ep[j] + dk * DK + d4);
                #pragma unroll
                for (int i = 0; i < 4; ++i) {
                    #pragma unroll
                    for (int j = 0; j < 8; ++j) {
                        acc[i][j] = fmaf(xv[i].x, ev[j].x, acc[i][j]);
                        acc[i][j] = fmaf(xv[i].y, ev[j].y, acc[i][j]);
                        acc[i][j] = fmaf(xv[i].z, ev[j].z, acc[i][j]);
                        acc[i][j] = fmaf(xv[i].w, ev[j].w, acc[i][j]);
                    }
                }
            }
        }

        {
#pragma clang fp contract(off)
            #pragma unroll
            for (int j = 0; j < 8; ++j) {
                const int c = cc * BN + tc + 16 * j;
                const float es = esq[c];
                #pragma unroll
                for (int i = 0; i < 4; ++i) {
                    const float t3 = xsqr[i] - 2.0f * acc[i][j];
                    const float v  = t3 + es;
                    if (v < bestv[i]) { bestv[i] = v; bestc[i] = c; }
                }
            }
        }
    }

    __syncthreads();
    float* rv = xs;
    int*   rc = reinterpret_cast<int*>(xs + BM * 16);
    #pragma unroll
    for (int i = 0; i < 4; ++i) {
        const int r = tr * 4 + i;
        rv[r * 16 + tc] = bestv[i];
        rc[r * 16 + tc] = bestc[i];
    }
    __syncthreads();
    if (t < BM) {
        float bv = rv[t * 16];
        int   bc = rc[t * 16];
        #pragma unroll
        for (int k = 1; k < 16; ++k) {
            const float v = rv[t * 16 + k];
            const int   cidx = rc[t * 16 + k];
            if (v < bv || (v == bv && cidx < bc)) { bv = v; bc = cidx; }
        }
        out[row0 + t] = bc;
    }
}

// ===========================================================================
extern "C" void kernel_launch(void* const* d_in, const int* in_sizes, int n_in,
                              void* d_out, int out_size, void* d_ws, size_t ws_size,
                              hipStream_t stream) {
    const float* x  = (const float*)d_in[0];   // [32, 256, 32, 32]
    const float* cb = (const float*)d_in[1];   // [1024, 256]
    int* out = (int*)d_out;                    // [32768] int32
    float* ws = (float*)d_ws;

    if (ws_size >= WS_NEED_BYTES) {
        float4* et4  = (float4*)(ws + WS_ET);
        float*  esq  = ws + WS_ESQ;
        float*  xsq  = ws + WS_XSQ;
        float2* cand = (float2*)(ws + WS_CAND);

        vq_xsq_kernel<<<NROWS / 256, 256, 0, stream>>>(x, xsq);
        vq_esq_kernel<<<K_CODES / 256, 256, 0, stream>>>(cb, esq);
        vq_tr4_kernel<<<256, 256, 0, stream>>>(cb, et4);
        vq_main5_kernel<<<(NROWS / ROWS_PER_WAVE) * NGROUPS / 4, 256, 0, stream>>>(
            x, et4, esq, xsq, cand);
        vq_reduce_kernel<<<NROWS / 256, 256, 0, stream>>>(cand, out);
    } else {
        float* esq = ws;
        float* xsq = ws + K_CODES;
        vq_xsq_kernel<<<NROWS / 256, 256, 0, stream>>>(x, xsq);
        vq_esq_kernel<<<K_CODES / 256, 256, 0, stream>>>(cb, esq);
        vq_main_kernel<<<NROWS / BM, 256, 0, stream>>>(x, cb, esq, xsq, out);
    }
}

// Round 11
// 228.558 us; speedup vs baseline: 6.2517x; 1.0515x over previous
//
#include <hip/hip_runtime.h>

#define K_CODES 1024
#define DIMS    256
#define NROWS   32768   // B*H*W = 32*32*32

// ---------------- main-path geometry ----------------
#define NGROUPS       2      // code groups of 512 (8 codes per lane)
#define ROWS_PER_WAVE 16     // 2048 slices x 2 groups = 4096 waves, 1024 blocks
#define RP            16     // rows per (single) pass

// ws layout (float units)
#define WS_ET    0
#define WS_ESQ   (WS_ET  + DIMS * K_CODES)        // 262144 (et4: 64 x 1024 float4)
#define WS_XSQ   (WS_ESQ + K_CODES)               // +1024
#define WS_CAND  (WS_XSQ + NROWS)                 // +32768
#define WS_NEED_FLOATS (WS_CAND + NGROUPS * NROWS * 2)
#define WS_NEED_BYTES  ((size_t)WS_NEED_FLOATS * 4)

// ---------------------------------------------------------------------------
// numpy-bitwise sum of squares of a 256-element row (verified round 2).
// ---------------------------------------------------------------------------
__device__ __forceinline__ float sq_at(const float* p, int d, int stride) {
#pragma clang fp contract(off)
    const float v = p[(size_t)d * stride];
    return v * v;
}

__device__ __forceinline__ float np_block_sq(const float* p, int stride, int o, int n) {
#pragma clang fp contract(off)
    float r[8];
    #pragma unroll
    for (int k = 0; k < 8; ++k) r[k] = sq_at(p, o + k, stride);
    const int n8 = n - (n % 8);
    for (int i = 8; i < n8; i += 8) {
        #pragma unroll
        for (int k = 0; k < 8; ++k) r[k] = r[k] + sq_at(p, o + i + k, stride);
    }
    float res = ((r[0] + r[1]) + (r[2] + r[3])) + ((r[4] + r[5]) + (r[6] + r[7]));
    for (int i = n8; i < n; ++i) res = res + sq_at(p, o + i, stride);
    return res;
}

__device__ __forceinline__ float np_sumsq_row(const float* p, int stride) {
#pragma clang fp contract(off)
    const float p120 = np_block_sq(p, stride, 1,   120);
    const float p64  = np_block_sq(p, stride, 121, 64);
    const float p71  = np_block_sq(p, stride, 185, 71);
    const float s135 = p64 + p71;
    const float s255 = p120 + s135;
    return sq_at(p, 0, stride) + s255;
}

// ---------------- merged prologue: xsq (128 blk) + esq (4 blk) + tr4 (256 blk)
__global__ void vq_prologue_kernel(const float* __restrict__ x, const float* __restrict__ cb,
                                   float* __restrict__ xsq, float* __restrict__ esq,
                                   float4* __restrict__ et4) {
    const int bid = blockIdx.x;
    if (bid < 128) {                                   // xsq: 32768 rows
        const int n = bid * 256 + threadIdx.x;
        const float* p = x + ((size_t)(n >> 10)) * (DIMS * 1024) + (n & 1023);
        xsq[n] = np_sumsq_row(p, 1024);
    } else if (bid < 132) {                            // esq: 1024 codes
        const int c = (bid - 128) * 256 + threadIdx.x;
        esq[c] = np_sumsq_row(cb + (size_t)c * DIMS, 1);
    } else {                                           // et4[dk][c] panel transpose
        const int idx = (bid - 132) * 256 + threadIdx.x;   // 65536 = 64 dk x 1024 c
        const int dk  = idx & 63;
        const int c   = idx >> 6;
        const float4 v = *reinterpret_cast<const float4*>(cb + (size_t)c * DIMS + dk * 4);
        et4[(size_t)dk * K_CODES + c] = v;
    }
}

// ---------------- main v6: 8 codes/lane x 16 rows, panel e-loads, ping-pong --
// Per dk-step: 512 FMAs amortize {8 dwordx4 e-loads, 4 s_load_dwordx16 x-loads,
// loop/addressing} — halves both the issue overhead per FMA and the
// once-per-body SMEM-latency exposure that capped round 10 at 74% busy.
// Register tile ~200 VGPR (acc 128 + e ping-pong 64): launch_bounds(256,2)
// caps at 256 so the allocator can allocate honestly (rounds 6-8 lesson);
// expected occupancy 2 waves/SIMD — tolerated by the 512-FMA runs.
// FMA chain per (row,code): one accumulator, strictly ascending d (dk asc,
// dd asc) -> bitwise identical to the np/BLAS reference order.
__global__ __launch_bounds__(256, 2)
void vq_main6_kernel(const float* __restrict__ x, const float4* __restrict__ et4,
                     const float* __restrict__ esq, const float* __restrict__ xsq,
                     float2* __restrict__ cand) {
    const int wid  = __builtin_amdgcn_readfirstlane((int)(threadIdx.x >> 6));
    const int lane = threadIdx.x & 63;
    const int W     = blockIdx.x * 4 + wid;        // 0..4095
    const int g     = W & (NGROUPS - 1);           // code group of 512
    const int slice = W >> 1;                      // 0..2047 row slice
    const int c0    = g * 512 + lane;              // lane codes: c0 + 64*j, j=0..7
    const int row_base = slice * ROWS_PER_WAVE;    // 16 | 1024 -> one image
    const int b    = row_base >> 10;
    const int hw0  = row_base & 1023;
    const float* xb = x + (size_t)b * (DIMS * 1024) + hw0;   // + d*1024 + r

    float esqv[8];
    #pragma unroll
    for (int j = 0; j < 8; ++j) esqv[j] = esq[c0 + 64 * j];

    float acc[8][RP];
    #pragma unroll
    for (int j = 0; j < 8; ++j)
        #pragma unroll
        for (int r = 0; r < RP; ++r) acc[j][r] = 0.0f;

    // e ping-pong buffers: 8 codes x 4 dims each (constant-indexed)
    float eA[32], eB[32];

#define LOAD_E(BUF, DK)                                                         \
    do {                                                                        \
        const float4* p_ = et4 + (size_t)(DK) * K_CODES;                        \
        _Pragma("unroll")                                                       \
        for (int j = 0; j < 8; ++j)                                             \
            *reinterpret_cast<float4*>(&BUF[4 * j]) = p_[c0 + 64 * j];          \
    } while (0)

    // per dim: 16 wave-uniform x loads (s_load_dwordx16) feed 128 FMAs.
#define COMPUTE(DK, E)                                                          \
    do {                                                                        \
        _Pragma("unroll")                                                       \
        for (int dd = 0; dd < 4; ++dd) {                                        \
            float xv[RP];                                                       \
            _Pragma("unroll")                                                   \
            for (int r = 0; r < RP; ++r)                                        \
                xv[r] = xb[(size_t)((DK) * 4 + dd) * 1024 + r];                 \
            _Pragma("unroll")                                                   \
            for (int j = 0; j < 8; ++j) {                                       \
                _Pragma("unroll")                                               \
                for (int r = 0; r < RP; ++r)                                    \
                    acc[j][r] = fmaf(xv[r], E[4 * j + dd], acc[j][r]);          \
            }                                                                   \
        }                                                                       \
    } while (0)

    LOAD_E(eA, 0);
    for (int dk = 0; dk < DIMS / 4; dk += 2) {
        LOAD_E(eB, dk + 1);
        COMPUTE(dk, eA);
        if (dk + 2 < DIMS / 4) LOAD_E(eA, dk + 2);
        COMPUTE(dk + 1, eB);
    }
#undef LOAD_E
#undef COMPUTE

    // epilogue: d2 = fl(fl(x_sq - 2*dot) + e_sq), exact np op order;
    // in-lane combine ascending c (strict < -> lower code wins ties),
    // then exact first-index 64-lane lexmin butterfly.
    {
#pragma clang fp contract(off)
        float keepv = 0.0f; int keepc = 0;
        #pragma unroll
        for (int r = 0; r < RP; ++r) {
            const float xs_r = xsq[row_base + r];            // uniform
            float bv = (xs_r - 2.0f * acc[0][r]) + esqv[0];
            int   bc = c0;
            #pragma unroll
            for (int j = 1; j < 8; ++j) {
                const float vj = (xs_r - 2.0f * acc[j][r]) + esqv[j];
                if (vj < bv) { bv = vj; bc = c0 + 64 * j; }
            }
            #pragma unroll
            for (int off = 1; off < 64; off <<= 1) {
                const float ov = __shfl_xor(bv, off, 64);
                const int   oc = __shfl_xor(bc, off, 64);
                if (ov < bv || (ov == bv && oc < bc)) { bv = ov; bc = oc; }
            }
            if (lane == r) { keepv = bv; keepc = bc; }       // lane r keeps row r
        }
        if (lane < RP) {
            cand[(size_t)g * NROWS + row_base + lane] =
                make_float2(keepv, __int_as_float(keepc));
        }
    }
}

// ---------------- cross-group lexmin reduce (groups ascending in code) ------
__global__ void vq_reduce_kernel(const float2* __restrict__ cand, int* __restrict__ out) {
    const int row = blockIdx.x * 256 + threadIdx.x;
    float2 p = cand[row];
    float bv = p.x; int bc = __float_as_int(p.y);
    #pragma unroll
    for (int gg = 1; gg < NGROUPS; ++gg) {
        const float2 q = cand[(size_t)gg * NROWS + row];
        const float v = q.x; const int qc = __float_as_int(q.y);
        if (v < bv || (v == bv && qc < bc)) { bv = v; bc = qc; }
    }
    out[row] = bc;
}

// ===========================================================================
// Fallback path (round-2 kernel, verified passing) — used if ws too small.
// ===========================================================================
#define BM      64
#define BN      128
#define DK      32
#define PITCH   36

__global__ void vq_xsq_kernel(const float* __restrict__ x, float* __restrict__ xsq) {
    const int n = blockIdx.x * 256 + threadIdx.x;
    const float* p = x + ((size_t)(n >> 10)) * (DIMS * 1024) + (n & 1023);
    xsq[n] = np_sumsq_row(p, 1024);
}

__global__ void vq_esq_kernel(const float* __restrict__ cb, float* __restrict__ esq) {
    const int c = blockIdx.x * 256 + threadIdx.x;
    esq[c] = np_sumsq_row(cb + (size_t)c * DIMS, 1);
}

__global__ __launch_bounds__(256, 2)
void vq_main_kernel(const float* __restrict__ x, const float* __restrict__ cb,
                    const float* __restrict__ esq, const float* __restrict__ xsq,
                    int* __restrict__ out) {
    __shared__ float xs[BM * PITCH];

    const int t   = threadIdx.x;
    const int tc  = t & 15;
    const int tr  = t >> 4;
    const int row0 = blockIdx.x * BM;
    const int b   = row0 >> 10;
    const int hw0 = row0 & 1023;
    const float* xb = x + (size_t)b * DIMS * 1024 + hw0;

    float xsqr[4];
    #pragma unroll
    for (int i = 0; i < 4; ++i) xsqr[i] = xsq[row0 + tr * 4 + i];

    float bestv[4];
    int   bestc[4];
    #pragma unroll
    for (int i = 0; i < 4; ++i) { bestv[i] = 3.4e38f; bestc[i] = 0; }

    for (int cc = 0; cc < K_CODES / BN; ++cc) {
        const float* ep[8];
        #pragma unroll
        for (int j = 0; j < 8; ++j)
            ep[j] = cb + (size_t)(cc * BN + tc + 16 * j) * DIMS;

        float acc[4][8];
        #pragma unroll
        for (int i = 0; i < 4; ++i)
            #pragma unroll
            for (int j = 0; j < 8; ++j) acc[i][j] = 0.0f;

        for (int dk = 0; dk < DIMS / DK; ++dk) {
            __syncthreads();
            #pragma unroll
            for (int ii = 0; ii < 2; ++ii) {
                const int li = t + 256 * ii;
                const int d  = (li >> 2) & 31;
                const int h4 = (li & 3) | ((li >> 7) << 2);
                const float4 v = *reinterpret_cast<const float4*>(
                    xb + (size_t)(dk * DK + d) * 1024 + h4 * 4);
                xs[(h4 * 4 + 0) * PITCH + d] = v.x;
                xs[(h4 * 4 + 1) * PITCH + d] = v.y;
                xs[(h4 * 4 + 2) * PITCH + d] = v.z;
                xs[(h4 * 4 + 3) * PITCH + d] = v.w;
            }
            __syncthreads();

            #pragma unroll
            for (int d4 = 0; d4 < DK; d4 += 4) {
                float4 xv[4];
                #pragma unroll
                for (int i = 0; i < 4; ++i)
                    xv[i] = *reinterpret_cast<const float4*>(&xs[(tr * 4 + i) * PITCH + d4]);
                float4 ev[8];
                #pragma unroll
                for (int j = 0; j < 8; ++j)
                    ev[j] = *reinterpret_cast<const float4*>(ep[j] + dk * DK + d4);
                #pragma unroll
                for (int i = 0; i < 4; ++i) {
                    #pragma unroll
                    for (int j = 0; j < 8; ++j) {
                        acc[i][j] = fmaf(xv[i].x, ev[j].x, acc[i][j]);
                        acc[i][j] = fmaf(xv[i].y, ev[j].y, acc[i][j]);
                        acc[i][j] = fmaf(xv[i].z, ev[j].z, acc[i][j]);
                        acc[i][j] = fmaf(xv[i].w, ev[j].w, acc[i][j]);
                    }
                }
            }
        }

        {
#pragma clang fp contract(off)
            #pragma unroll
            for (int j = 0; j < 8; ++j) {
                const int c = cc * BN + tc + 16 * j;
                const float es = esq[c];
                #pragma unroll
                for (int i = 0; i < 4; ++i) {
                    const float t3 = xsqr[i] - 2.0f * acc[i][j];
                    const float v  = t3 + es;
                    if (v < bestv[i]) { bestv[i] = v; bestc[i] = c; }
                }
            }
        }
    }

    __syncthreads();
    float* rv = xs;
    int*   rc = reinterpret_cast<int*>(xs + BM * 16);
    #pragma unroll
    for (int i = 0; i < 4; ++i) {
        const int r = tr * 4 + i;
        rv[r * 16 + tc] = bestv[i];
        rc[r * 16 + tc] = bestc[i];
    }
    __syncthreads();
    if (t < BM) {
        float bv = rv[t * 16];
        int   bc = rc[t * 16];
        #pragma unroll
        for (int k = 1; k < 16; ++k) {
            const float v = rv[t * 16 + k];
            const int   cidx = rc[t * 16 + k];
            if (v < bv || (v == bv && cidx < bc)) { bv = v; bc = cidx; }
        }
        out[row0 + t] = bc;
    }
}

// ===========================================================================
extern "C" void kernel_launch(void* const* d_in, const int* in_sizes, int n_in,
                              void* d_out, int out_size, void* d_ws, size_t ws_size,
                              hipStream_t stream) {
    const float* x  = (const float*)d_in[0];   // [32, 256, 32, 32]
    const float* cb = (const float*)d_in[1];   // [1024, 256]
    int* out = (int*)d_out;                    // [32768] int32
    float* ws = (float*)d_ws;

    if (ws_size >= WS_NEED_BYTES) {
        float4* et4  = (float4*)(ws + WS_ET);
        float*  esq  = ws + WS_ESQ;
        float*  xsq  = ws + WS_XSQ;
        float2* cand = (float2*)(ws + WS_CAND);

        vq_prologue_kernel<<<128 + 4 + 256, 256, 0, stream>>>(x, cb, xsq, esq, et4);
        vq_main6_kernel<<<(NROWS / ROWS_PER_WAVE) * NGROUPS / 4, 256, 0, stream>>>(
            x, et4, esq, xsq, cand);
        vq_reduce_kernel<<<NROWS / 256, 256, 0, stream>>>(cand, out);
    } else {
        float* esq = ws;
        float* xsq = ws + K_CODES;
        vq_xsq_kernel<<<NROWS / 256, 256, 0, stream>>>(x, xsq);
        vq_esq_kernel<<<K_CODES / 256, 256, 0, stream>>>(cb, esq);
        vq_main_kernel<<<NROWS / BM, 256, 0, stream>>>(x, cb, esq, xsq, out);
    }
}